// Round 9
// baseline (178.567 us; speedup 1.0000x reference)
//
#include <hip/hip_runtime.h>

#define L 256
#define D 256
#define H 8
#define DH 32

static constexpr float NEGV = -4294967296.0f;       // fp32(-(2^32)+1)
static constexpr float INV_SQRT_DH = 0.17677669529663687f;  // 1/sqrt(32)

// ---------------------------------------------------------------------------
// Fused QKV projection: out = A @ W + bias (+ add)
// ---------------------------------------------------------------------------
__global__ __launch_bounds__(256) void proj3_kernel(
    const float* __restrict__ queries, const float* __restrict__ keys,
    const float* __restrict__ Wq, const float* __restrict__ bq,
    const float* __restrict__ Wk, const float* __restrict__ bk,
    const float* __restrict__ Wv, const float* __restrict__ bv,
    const float* __restrict__ pk, const float* __restrict__ pv,
    float* __restrict__ Qo, float* __restrict__ KPko, float* __restrict__ VPvo)
{
    __shared__ float As[16][68];
    __shared__ float Bs[16][64];

    const float* A; const float* W; const float* bias; const float* add; float* out;
    if (blockIdx.z == 0)      { A = queries; W = Wq; bias = bq; add = nullptr; out = Qo; }
    else if (blockIdx.z == 1) { A = keys;    W = Wk; bias = bk; add = pk;      out = KPko; }
    else                      { A = keys;    W = Wv; bias = bv; add = pv;      out = VPvo; }

    const int t  = threadIdx.x;
    const int bm = blockIdx.x * 64;
    const int bn = blockIdx.y * 64;

    const int ar = t >> 2;
    const int ak = (t & 3) << 2;
    const int br = t >> 4;
    const int bc = (t & 15) << 2;
    const int tm = (t >> 4) << 2;
    const int tn = (t & 15) << 2;

    float acc[4][4] = {};

    for (int k0 = 0; k0 < 256; k0 += 16) {
        const float4 a4 = *(const float4*)&A[(bm + ar) * 256 + k0 + ak];
        const float4 b4 = *(const float4*)&W[(k0 + br) * 256 + bn + bc];
        As[ak + 0][ar] = a4.x; As[ak + 1][ar] = a4.y;
        As[ak + 2][ar] = a4.z; As[ak + 3][ar] = a4.w;
        *(float4*)&Bs[br][bc] = b4;
        __syncthreads();

        #pragma unroll
        for (int kk = 0; kk < 16; ++kk) {
            const float4 a = *(const float4*)&As[kk][tm];
            const float4 bb = *(const float4*)&Bs[kk][tn];
            const float aa[4] = {a.x, a.y, a.z, a.w};
            const float bbv[4] = {bb.x, bb.y, bb.z, bb.w};
            #pragma unroll
            for (int i = 0; i < 4; ++i)
                #pragma unroll
                for (int jj = 0; jj < 4; ++jj)
                    acc[i][jj] = fmaf(aa[i], bbv[jj], acc[i][jj]);
        }
        __syncthreads();
    }

    const float4 bias4 = *(const float4*)&bias[bn + tn];
    #pragma unroll
    for (int i = 0; i < 4; ++i) {
        const int row = bm + tm + i;
        float4 o;
        o.x = acc[i][0] + bias4.x; o.y = acc[i][1] + bias4.y;
        o.z = acc[i][2] + bias4.z; o.w = acc[i][3] + bias4.w;
        if (add) {
            const float4 a4 = *(const float4*)&add[row * 256 + bn + tn];
            o.x += a4.x; o.y += a4.y; o.z += a4.z; o.w += a4.w;
        }
        *(float4*)&out[row * 256 + bn + tn] = o;
    }
}

// ---------------------------------------------------------------------------
// Row-sum masks.
// ---------------------------------------------------------------------------
__global__ __launch_bounds__(256) void mask_kernel(
    const float* __restrict__ keys, const float* __restrict__ queries,
    float* __restrict__ kmask, float* __restrict__ qmask)
{
    const int wid  = (blockIdx.x * 256 + threadIdx.x) >> 6;
    const int lane = threadIdx.x & 63;
    const float* src = (wid < 2048) ? keys : queries;
    const int row = (wid < 2048) ? wid : (wid - 2048);

    const float4 v = *(const float4*)&src[row * 256 + (lane << 2)];
    float s = v.x + v.y + v.z + v.w;
    #pragma unroll
    for (int o = 1; o < 64; o <<= 1) s += __shfl_xor(s, o);
    if (lane == 0) {
        const float m = (s != 0.0f) ? 1.0f : 0.0f;
        if (wid < 2048) kmask[row] = m; else qmask[row] = m;
    }
}

// ---------------------------------------------------------------------------
// S0[b][q][h][k] = dot_32(Qh[b,q,h,:], KPkh[b,k,h,:])  (raw, unscaled)
// grid (4 qtiles, 4 ktiles, 64 bh), 256 threads, 64x64 tile, K=32.
// ---------------------------------------------------------------------------
__global__ __launch_bounds__(256) void qk0_kernel(
    const float* __restrict__ Qm, const float* __restrict__ KPk,
    float* __restrict__ S0)
{
    const int bh = blockIdx.z;
    const int b  = bh >> 3, h = bh & 7;
    const int q0 = blockIdx.x << 6;
    const int k0 = blockIdx.y << 6;
    const int t  = threadIdx.x;

    __shared__ float Qs[32][65];   // [d][q]
    __shared__ float Ks[32][65];   // [d][k]

    {
        const int r = t >> 2;               // 0..63
        const int c = (t & 3) << 3;         // 0,8,16,24
        const float* qp = &Qm [((b << 8) + q0 + r) * 256 + (h << 5) + c];
        const float* kp = &KPk[((b << 8) + k0 + r) * 256 + (h << 5) + c];
        const float4 a0 = *(const float4*)qp, a1 = *(const float4*)(qp + 4);
        const float4 b0 = *(const float4*)kp, b1 = *(const float4*)(kp + 4);
        Qs[c+0][r]=a0.x; Qs[c+1][r]=a0.y; Qs[c+2][r]=a0.z; Qs[c+3][r]=a0.w;
        Qs[c+4][r]=a1.x; Qs[c+5][r]=a1.y; Qs[c+6][r]=a1.z; Qs[c+7][r]=a1.w;
        Ks[c+0][r]=b0.x; Ks[c+1][r]=b0.y; Ks[c+2][r]=b0.z; Ks[c+3][r]=b0.w;
        Ks[c+4][r]=b1.x; Ks[c+5][r]=b1.y; Ks[c+6][r]=b1.z; Ks[c+7][r]=b1.w;
    }
    __syncthreads();

    const int tq = (t >> 4) << 2;
    const int tk = (t & 15) << 2;
    float acc[4][4] = {};
    #pragma unroll
    for (int d = 0; d < 32; ++d) {
        const float qa[4] = {Qs[d][tq], Qs[d][tq+1], Qs[d][tq+2], Qs[d][tq+3]};
        const float kb[4] = {Ks[d][tk], Ks[d][tk+1], Ks[d][tk+2], Ks[d][tk+3]};
        #pragma unroll
        for (int i = 0; i < 4; ++i)
            #pragma unroll
            for (int jj = 0; jj < 4; ++jj)
                acc[i][jj] = fmaf(qa[i], kb[jj], acc[i][jj]);
    }

    #pragma unroll
    for (int i = 0; i < 4; ++i) {
        float4 o = make_float4(acc[i][0], acc[i][1], acc[i][2], acc[i][3]);
        *(float4*)&S0[(size_t)((b << 8) + q0 + tq + i) * 2048 + (h << 8) + k0 + tk] = o;
    }
}

// ---------------------------------------------------------------------------
// Streaming attention: one block (256 thr / 4 waves) per (b,q), parity remap.
// Phase B streams ONLY Tk rows (S0 staged in LDS); softmax in LDS; writes
// softmax'd A row (in-place over S0); Phase C streams ONLY Tv rows -> Ostr.
// ---------------------------------------------------------------------------
#define LP (L + 4)

__global__ __launch_bounds__(256) void attn_stream_kernel(
    const float* __restrict__ Qm, const float* __restrict__ S0A_in,
    float* __restrict__ S0A, const float* __restrict__ Tk,
    const float* __restrict__ Tv, const float* __restrict__ kmask,
    float* __restrict__ Ostr)
{
    const int bid = blockIdx.x;
    const int b   = bid >> 8;
    const int j0  = bid & 255;
    const int q   = (b & 1) ? (255 - j0) : j0;   // balance causal work per CU
    const int bq  = (b << 8) + q;
    const int t    = threadIdx.x;
    const int w    = t >> 6;
    const int lane = t & 63;

    __shared__ float qrow[D];
    __shared__ float kmrow[L];
    __shared__ float sc[H][LP];
    __shared__ int   allneg[H];
    __shared__ float4 red[256];

    qrow[t]  = Qm[bq * D + t];
    kmrow[t] = kmask[(b << 8) + t];
    // stage S0 row; k>q positions -> NEGV (causal)
    {
        const float* s0row = &S0A_in[(size_t)bq << 11];
        #pragma unroll
        for (int i = t; i < 2048; i += 256) {
            const int k = i & 255;
            sc[i >> 8][k] = (k <= q) ? s0row[i] : NEGV;
        }
    }
    __syncthreads();

    // ---- Phase B: stream Tk rows only.
    const int hB = lane >> 3;
    const int jB = lane & 7;
    const size_t tbase = (size_t)bq << 16;
    const float4 qv = *(const float4*)&qrow[lane << 2];

    #pragma unroll 2
    for (int k = w; k <= q; k += 4) {
        const float4 tkv = *(const float4*)&Tk[tbase + ((size_t)k << 8) + (lane << 2)];
        float p = qv.x * tkv.x;
        p = fmaf(qv.y, tkv.y, p);
        p = fmaf(qv.z, tkv.z, p);
        p = fmaf(qv.w, tkv.w, p);
        p += __shfl_xor(p, 1);
        p += __shfl_xor(p, 2);
        p += __shfl_xor(p, 4);
        if (jB == 0)
            sc[hB][k] = (kmrow[k] != 0.0f) ? (sc[hB][k] + p) * INV_SQRT_DH : NEGV;
    }
    __syncthreads();

    // ---- Softmax (handles all-NEG rows -> uniform 1/256 automatically).
    #pragma unroll
    for (int hh = 0; hh < 2; ++hh) {
        const int h = (w << 1) + hh;
        float v0 = sc[h][lane];
        float v1 = sc[h][lane + 64];
        float v2 = sc[h][lane + 128];
        float v3 = sc[h][lane + 192];
        float m = fmaxf(fmaxf(v0, v1), fmaxf(v2, v3));
        #pragma unroll
        for (int o = 1; o < 64; o <<= 1) m = fmaxf(m, __shfl_xor(m, o));
        const float e0 = __expf(v0 - m), e1 = __expf(v1 - m);
        const float e2 = __expf(v2 - m), e3 = __expf(v3 - m);
        float s = e0 + e1 + e2 + e3;
        #pragma unroll
        for (int o = 1; o < 64; o <<= 1) s += __shfl_xor(s, o);
        const float r = 1.0f / s;
        sc[h][lane]       = e0 * r;
        sc[h][lane + 64]  = e1 * r;
        sc[h][lane + 128] = e2 * r;
        sc[h][lane + 192] = e3 * r;
        if (lane == 0) allneg[h] = (m == NEGV) ? 1 : 0;
    }
    __syncthreads();

    // write A row (coalesced, in-place over S0)
    {
        float* arow = &S0A[(size_t)bq << 11];
        #pragma unroll
        for (int i = t; i < 2048; i += 256)
            arow[i] = sc[i >> 8][i & 255];
    }

    // ---- Phase C: stream Tv rows only.
    const int dg = lane;
    const int h  = dg >> 3;
    const int kmax = allneg[h] ? L : (q + 1);

    float4 acc = make_float4(0.f, 0.f, 0.f, 0.f);
    #pragma unroll 2
    for (int k = w; k < kmax; k += 4) {
        const float a = sc[h][k];
        const float4 tvv = *(const float4*)&Tv[tbase + ((size_t)k << 8) + (dg << 2)];
        acc.x = fmaf(a, tvv.x, acc.x);
        acc.y = fmaf(a, tvv.y, acc.y);
        acc.z = fmaf(a, tvv.z, acc.z);
        acc.w = fmaf(a, tvv.w, acc.w);
    }
    red[t] = acc;
    __syncthreads();

    if (t < 64) {
        const float4 r0 = red[t], r1 = red[t + 64], r2 = red[t + 128], r3 = red[t + 192];
        float4 o;
        o.x = r0.x + r1.x + r2.x + r3.x;
        o.y = r0.y + r1.y + r2.y + r3.y;
        o.z = r0.z + r1.z + r2.z + r3.z;
        o.w = r0.w + r1.w + r2.w + r3.w;
        *(float4*)&Ostr[bq * 256 + (t << 2)] = o;
    }
}

// ---------------------------------------------------------------------------
// O = (Ostr + A·VPvh)·qmask + queries, per (b,h,qtile).
// grid 512: bid = bh*8 + qt (32 q per block). V tile staged in LDS.
// ---------------------------------------------------------------------------
__global__ __launch_bounds__(256) void av_kernel(
    const float* __restrict__ A, const float* __restrict__ VPv,
    const float* __restrict__ Ostr, const float* __restrict__ qmask,
    const float* __restrict__ queries, float* __restrict__ out)
{
    const int bid = blockIdx.x;
    const int bh  = bid >> 3;
    const int b   = bh >> 3, h = bh & 7;
    const int q0  = (bid & 7) << 5;
    const int t   = threadIdx.x;

    __shared__ float Vs[256][40];   // row stride 160B (16B-aligned), padded

    // stage VPvh [256][32]
    #pragma unroll
    for (int r = 0; r < 8; ++r) {
        const int row = (t >> 3) + (r << 5);
        const int c   = (t & 7) << 2;
        *(float4*)&Vs[row][c] =
            *(const float4*)&VPv[((b << 8) + row) * 256 + (h << 5) + c];
    }
    __syncthreads();

    const int ql = t >> 3;            // 0..31 local q
    const int d4 = (t & 7) << 2;      // 0..28
    const int qg = q0 + ql;
    const int bqg = (b << 8) + qg;
    const float* arow = &A[(size_t)bqg * 2048 + (h << 8)];

    float4 acc = make_float4(0.f, 0.f, 0.f, 0.f);
    #pragma unroll 4
    for (int k = 0; k < 256; ++k) {
        const float a = arow[k];
        const float4 v = *(const float4*)&Vs[k][d4];
        acc.x = fmaf(a, v.x, acc.x);
        acc.y = fmaf(a, v.y, acc.y);
        acc.z = fmaf(a, v.z, acc.z);
        acc.w = fmaf(a, v.w, acc.w);
    }

    const int idx = bqg * 256 + (h << 5) + d4;
    const float qmv = qmask[bqg];
    const float4 os = *(const float4*)&Ostr[idx];
    const float4 qv = *(const float4*)&queries[idx];
    float4 o;
    o.x = (os.x + acc.x) * qmv + qv.x;
    o.y = (os.y + acc.y) * qmv + qv.y;
    o.z = (os.z + acc.z) * qmv + qv.z;
    o.w = (os.w + acc.w) * qmv + qv.w;
    *(float4*)&out[idx] = o;
}

// ---------------------------------------------------------------------------
extern "C" void kernel_launch(void* const* d_in, const int* in_sizes, int n_in,
                              void* d_out, int out_size, void* d_ws, size_t ws_size,
                              hipStream_t stream)
{
    const float* queries = (const float*)d_in[0];
    const float* keys    = (const float*)d_in[1];
    const float* Tk      = (const float*)d_in[2];
    const float* Tv      = (const float*)d_in[3];
    const float* pk      = (const float*)d_in[4];
    const float* pv      = (const float*)d_in[5];
    const float* Wq      = (const float*)d_in[6];
    const float* bq      = (const float*)d_in[7];
    const float* Wk      = (const float*)d_in[8];
    const float* bk      = (const float*)d_in[9];
    const float* Wv      = (const float*)d_in[10];
    const float* bv      = (const float*)d_in[11];
    float* out = (float*)d_out;

    float* ws   = (float*)d_ws;
    float* Q    = ws;                    // 524288
    float* KPk  = ws + 524288;           // 524288
    float* VPv  = ws + 1048576;          // 524288
    float* km   = ws + 1572864;          // 2048
    float* qm   = ws + 1574912;          // 2048
    float* S0A  = ws + 1576960;          // 2048*2048 = 4194304 (scores then A)
    float* Ostr = ws + 5771264;          // 524288

    dim3 pgrid(2048 / 64, 256 / 64, 3);
    proj3_kernel<<<pgrid, 256, 0, stream>>>(queries, keys, Wq, bq, Wk, bk,
                                            Wv, bv, pk, pv, Q, KPk, VPv);
    mask_kernel<<<1024, 256, 0, stream>>>(keys, queries, km, qm);
    dim3 qgrid(4, 4, 64);
    qk0_kernel<<<qgrid, 256, 0, stream>>>(Q, KPk, S0A);
    attn_stream_kernel<<<2048, 256, 0, stream>>>(Q, S0A, S0A, Tk, Tv, km, Ostr);
    av_kernel<<<512, 256, 0, stream>>>(S0A, VPv, Ostr, qm, queries, out);
}

// Round 10
// 140.632 us; speedup vs baseline: 1.2697x; 1.2697x over previous
//
#include <hip/hip_runtime.h>

#define L 256
#define D 256
#define H 8
#define DH 32

static constexpr float NEGV = -4294967296.0f;       // fp32(-(2^32)+1)
static constexpr float INV_SQRT_DH = 0.17677669529663687f;  // 1/sqrt(32)

// ---------------------------------------------------------------------------
// Fused QKV projection + row-sum masks: out = A @ W + bias (+ add)
// z=0: Q   = queries@Wq + bq          (bn==0 blocks also emit qmask)
// z=1: KPk = keys@Wk + bk + posK      (bn==0 blocks also emit kmask)
// z=2: VPv = keys@Wv + bv + posV
// ---------------------------------------------------------------------------
__global__ __launch_bounds__(256) void proj3_kernel(
    const float* __restrict__ queries, const float* __restrict__ keys,
    const float* __restrict__ Wq, const float* __restrict__ bq,
    const float* __restrict__ Wk, const float* __restrict__ bk,
    const float* __restrict__ Wv, const float* __restrict__ bv,
    const float* __restrict__ pk, const float* __restrict__ pv,
    float* __restrict__ Qo, float* __restrict__ KPko, float* __restrict__ VPvo,
    float* __restrict__ kmask, float* __restrict__ qmask)
{
    __shared__ float As[16][68];
    __shared__ float Bs[16][64];

    const float* A; const float* W; const float* bias; const float* add; float* out;
    if (blockIdx.z == 0)      { A = queries; W = Wq; bias = bq; add = nullptr; out = Qo; }
    else if (blockIdx.z == 1) { A = keys;    W = Wk; bias = bk; add = pk;      out = KPko; }
    else                      { A = keys;    W = Wv; bias = bv; add = pv;      out = VPvo; }

    const int t  = threadIdx.x;
    const int bm = blockIdx.x * 64;
    const int bn = blockIdx.y * 64;

    const int ar = t >> 2;
    const int ak = (t & 3) << 2;
    const int br = t >> 4;
    const int bc = (t & 15) << 2;
    const int tm = (t >> 4) << 2;
    const int tn = (t & 15) << 2;

    float acc[4][4] = {};
    float msum = 0.0f;

    for (int k0 = 0; k0 < 256; k0 += 16) {
        const float4 a4 = *(const float4*)&A[(bm + ar) * 256 + k0 + ak];
        const float4 b4 = *(const float4*)&W[(k0 + br) * 256 + bn + bc];
        msum += a4.x + a4.y + a4.z + a4.w;
        As[ak + 0][ar] = a4.x; As[ak + 1][ar] = a4.y;
        As[ak + 2][ar] = a4.z; As[ak + 3][ar] = a4.w;
        *(float4*)&Bs[br][bc] = b4;
        __syncthreads();

        #pragma unroll
        for (int kk = 0; kk < 16; ++kk) {
            const float4 a = *(const float4*)&As[kk][tm];
            const float4 bb = *(const float4*)&Bs[kk][tn];
            const float aa[4] = {a.x, a.y, a.z, a.w};
            const float bbv[4] = {bb.x, bb.y, bb.z, bb.w};
            #pragma unroll
            for (int i = 0; i < 4; ++i)
                #pragma unroll
                for (int jj = 0; jj < 4; ++jj)
                    acc[i][jj] = fmaf(aa[i], bbv[jj], acc[i][jj]);
        }
        __syncthreads();
    }

    // fused row-sum mask (full A row = this block's 16 k-chunks x 4 lanes)
    if (blockIdx.y == 0 && blockIdx.z != 2) {
        float s = msum;
        s += __shfl_xor(s, 1);
        s += __shfl_xor(s, 2);
        if ((t & 3) == 0) {
            float* dst = (blockIdx.z == 0) ? qmask : kmask;
            dst[bm + (t >> 2)] = (s != 0.0f) ? 1.0f : 0.0f;
        }
    }

    const float4 bias4 = *(const float4*)&bias[bn + tn];
    #pragma unroll
    for (int i = 0; i < 4; ++i) {
        const int row = bm + tm + i;
        float4 o;
        o.x = acc[i][0] + bias4.x; o.y = acc[i][1] + bias4.y;
        o.z = acc[i][2] + bias4.z; o.w = acc[i][3] + bias4.w;
        if (add) {
            const float4 a4 = *(const float4*)&add[row * 256 + bn + tn];
            o.x += a4.x; o.y += a4.y; o.z += a4.z; o.w += a4.w;
        }
        *(float4*)&out[row * 256 + bn + tn] = o;
    }
}

// ---------------------------------------------------------------------------
// Fused attention (R3 structure). XCD-pinned mapping: b = bid & 7 so all
// blocks resident on XCD x work on batch x -> KPk_b/VPv_b/Q_b (~1MB) stay
// hot in that XCD's 4MB L2; only Tk/Tv stream through the fabric.
// q remap per XCD: g = ((j&192)>>1)|(j&31); q = (j&32) ? 255-g : g.
// Bijective; every stride-32 CU class gets pairs (q,255-q) -> 1028 rows/CU.
// ---------------------------------------------------------------------------
#define LP (L + 4)

__global__ __launch_bounds__(256) void attn_kernel(
    const float* __restrict__ Qm, const float* __restrict__ KPk,
    const float* __restrict__ VPv, const float* __restrict__ Tk,
    const float* __restrict__ Tv, const float* __restrict__ kmask,
    const float* __restrict__ qmask, const float* __restrict__ queries,
    float* __restrict__ out)
{
    const int bid = blockIdx.x;
    const int b   = bid & 7;                       // XCD-pinned batch
    const int j   = bid >> 3;                      // 0..255 within XCD
    const int g   = ((j & 192) >> 1) | (j & 31);
    const int q   = (j & 32) ? (255 - g) : g;
    const int bq  = (b << 8) + q;
    const int t    = threadIdx.x;
    const int w    = t >> 6;
    const int lane = t & 63;

    __shared__ float qrow[D];
    __shared__ float kmrow[L];
    __shared__ float sc[H][LP];
    __shared__ int   allneg[H];
    __shared__ float4 red[256];

    qrow[t]  = Qm[bq * D + t];
    kmrow[t] = kmask[(b << 8) + t];
    #pragma unroll
    for (int i = t; i < H * LP; i += 256) (&sc[0][0])[i] = NEGV;
    __syncthreads();

    // ---- Phase B: scores, block jointly streams consecutive KPk+Tk rows.
    const int hB = lane >> 3;
    const int jB = lane & 7;
    const size_t tbase = (size_t)bq << 16;
    const float4 qv = *(const float4*)&qrow[lane << 2];

    #pragma unroll 2
    for (int k = w; k <= q; k += 4) {
        const float4 kv  = *(const float4*)&KPk[((b << 8) + k) * 256 + (lane << 2)];
        const float4 tkv = *(const float4*)&Tk[tbase + ((size_t)k << 8) + (lane << 2)];
        float p = qv.x * (kv.x + tkv.x);
        p = fmaf(qv.y, kv.y + tkv.y, p);
        p = fmaf(qv.z, kv.z + tkv.z, p);
        p = fmaf(qv.w, kv.w + tkv.w, p);
        p += __shfl_xor(p, 1);
        p += __shfl_xor(p, 2);
        p += __shfl_xor(p, 4);
        if (jB == 0)
            sc[hB][k] = (kmrow[k] != 0.0f) ? p * INV_SQRT_DH : NEGV;
    }
    __syncthreads();

    // ---- Softmax: wave w handles heads 2w, 2w+1 (jax semantics).
    #pragma unroll
    for (int hh = 0; hh < 2; ++hh) {
        const int h = (w << 1) + hh;
        float v0 = sc[h][lane];
        float v1 = sc[h][lane + 64];
        float v2 = sc[h][lane + 128];
        float v3 = sc[h][lane + 192];
        float m = fmaxf(fmaxf(v0, v1), fmaxf(v2, v3));
        #pragma unroll
        for (int o = 1; o < 64; o <<= 1) m = fmaxf(m, __shfl_xor(m, o));
        const float e0 = __expf(v0 - m), e1 = __expf(v1 - m);
        const float e2 = __expf(v2 - m), e3 = __expf(v3 - m);
        float s = e0 + e1 + e2 + e3;
        #pragma unroll
        for (int o = 1; o < 64; o <<= 1) s += __shfl_xor(s, o);
        const float r = 1.0f / s;
        sc[h][lane]       = e0 * r;
        sc[h][lane + 64]  = e1 * r;
        sc[h][lane + 128] = e2 * r;
        sc[h][lane + 192] = e3 * r;
        if (lane == 0) allneg[h] = (m == NEGV) ? 1 : 0;
    }
    __syncthreads();

    // ---- Phase C: out = attn @ (VPv + Tv), 4-wave k-split.
    const int dg = lane;
    const int h  = dg >> 3;
    const int kmax = allneg[h] ? L : (q + 1);

    float4 acc = make_float4(0.f, 0.f, 0.f, 0.f);
    #pragma unroll 2
    for (int k = w; k < kmax; k += 4) {
        const float a = sc[h][k];
        const float4 v   = *(const float4*)&VPv[((b << 8) + k) * 256 + (dg << 2)];
        const float4 tvv = *(const float4*)&Tv[tbase + ((size_t)k << 8) + (dg << 2)];
        acc.x = fmaf(a, v.x + tvv.x, acc.x);
        acc.y = fmaf(a, v.y + tvv.y, acc.y);
        acc.z = fmaf(a, v.z + tvv.z, acc.z);
        acc.w = fmaf(a, v.w + tvv.w, acc.w);
    }
    red[t] = acc;
    __syncthreads();

    if (t < 64) {
        const float4 r0 = red[t], r1 = red[t + 64], r2 = red[t + 128], r3 = red[t + 192];
        const float qmv = qmask[bq];
        const float4 qv2 = *(const float4*)&queries[bq * 256 + (t << 2)];
        float4 o;
        o.x = (r0.x + r1.x + r2.x + r3.x) * qmv + qv2.x;
        o.y = (r0.y + r1.y + r2.y + r3.y) * qmv + qv2.y;
        o.z = (r0.z + r1.z + r2.z + r3.z) * qmv + qv2.z;
        o.w = (r0.w + r1.w + r2.w + r3.w) * qmv + qv2.w;
        *(float4*)&out[bq * 256 + (t << 2)] = o;
    }
}

// ---------------------------------------------------------------------------
extern "C" void kernel_launch(void* const* d_in, const int* in_sizes, int n_in,
                              void* d_out, int out_size, void* d_ws, size_t ws_size,
                              hipStream_t stream)
{
    const float* queries = (const float*)d_in[0];
    const float* keys    = (const float*)d_in[1];
    const float* Tk      = (const float*)d_in[2];
    const float* Tv      = (const float*)d_in[3];
    const float* pk      = (const float*)d_in[4];
    const float* pv      = (const float*)d_in[5];
    const float* Wq      = (const float*)d_in[6];
    const float* bq      = (const float*)d_in[7];
    const float* Wk      = (const float*)d_in[8];
    const float* bk      = (const float*)d_in[9];
    const float* Wv      = (const float*)d_in[10];
    const float* bv      = (const float*)d_in[11];
    float* out = (float*)d_out;

    float* ws  = (float*)d_ws;
    float* Q   = ws;                    // 2048*256
    float* KPk = ws + 524288;           // 2048*256
    float* VPv = ws + 1048576;          // 2048*256
    float* km  = ws + 1572864;          // 2048
    float* qm  = ws + 1574912;          // 2048

    dim3 pgrid(2048 / 64, 256 / 64, 3);
    proj3_kernel<<<pgrid, 256, 0, stream>>>(queries, keys, Wq, bq, Wk, bk,
                                            Wv, bv, pk, pv, Q, KPk, VPv,
                                            km, qm);
    attn_kernel<<<2048, 256, 0, stream>>>(Q, KPk, VPv, Tk, Tv, km, qm,
                                          queries, out);
}

// Round 11
// 137.524 us; speedup vs baseline: 1.2984x; 1.0226x over previous
//
#include <hip/hip_runtime.h>

#define L 256
#define D 256
#define H 8
#define DH 32

static constexpr float NEGV = -4294967296.0f;       // fp32(-(2^32)+1)
static constexpr float INV_SQRT_DH = 0.17677669529663687f;  // 1/sqrt(32)

// ---------------------------------------------------------------------------
// Fused QKV projection + row-sum masks: out = A @ W + bias (+ add)
// z=0: Q   = queries@Wq + bq          (bn==0 blocks also emit qmask)
// z=1: KPk = keys@Wk + bk + posK      (bn==0 blocks also emit kmask)
// z=2: VPv = keys@Wv + bv + posV
// ---------------------------------------------------------------------------
__global__ __launch_bounds__(256) void proj3_kernel(
    const float* __restrict__ queries, const float* __restrict__ keys,
    const float* __restrict__ Wq, const float* __restrict__ bq,
    const float* __restrict__ Wk, const float* __restrict__ bk,
    const float* __restrict__ Wv, const float* __restrict__ bv,
    const float* __restrict__ pk, const float* __restrict__ pv,
    float* __restrict__ Qo, float* __restrict__ KPko, float* __restrict__ VPvo,
    float* __restrict__ kmask, float* __restrict__ qmask)
{
    __shared__ float As[16][68];
    __shared__ float Bs[16][64];

    const float* A; const float* W; const float* bias; const float* add; float* out;
    if (blockIdx.z == 0)      { A = queries; W = Wq; bias = bq; add = nullptr; out = Qo; }
    else if (blockIdx.z == 1) { A = keys;    W = Wk; bias = bk; add = pk;      out = KPko; }
    else                      { A = keys;    W = Wv; bias = bv; add = pv;      out = VPvo; }

    const int t  = threadIdx.x;
    const int bm = blockIdx.x * 64;
    const int bn = blockIdx.y * 64;

    const int ar = t >> 2;
    const int ak = (t & 3) << 2;
    const int br = t >> 4;
    const int bc = (t & 15) << 2;
    const int tm = (t >> 4) << 2;
    const int tn = (t & 15) << 2;

    float acc[4][4] = {};
    float msum = 0.0f;

    for (int k0 = 0; k0 < 256; k0 += 16) {
        const float4 a4 = *(const float4*)&A[(bm + ar) * 256 + k0 + ak];
        const float4 b4 = *(const float4*)&W[(k0 + br) * 256 + bn + bc];
        msum += a4.x + a4.y + a4.z + a4.w;
        As[ak + 0][ar] = a4.x; As[ak + 1][ar] = a4.y;
        As[ak + 2][ar] = a4.z; As[ak + 3][ar] = a4.w;
        *(float4*)&Bs[br][bc] = b4;
        __syncthreads();

        #pragma unroll
        for (int kk = 0; kk < 16; ++kk) {
            const float4 a = *(const float4*)&As[kk][tm];
            const float4 bb = *(const float4*)&Bs[kk][tn];
            const float aa[4] = {a.x, a.y, a.z, a.w};
            const float bbv[4] = {bb.x, bb.y, bb.z, bb.w};
            #pragma unroll
            for (int i = 0; i < 4; ++i)
                #pragma unroll
                for (int jj = 0; jj < 4; ++jj)
                    acc[i][jj] = fmaf(aa[i], bbv[jj], acc[i][jj]);
        }
        __syncthreads();
    }

    // fused row-sum mask (full A row = this block's 16 k-chunks x 4 lanes)
    if (blockIdx.y == 0 && blockIdx.z != 2) {
        float s = msum;
        s += __shfl_xor(s, 1);
        s += __shfl_xor(s, 2);
        if ((t & 3) == 0) {
            float* dst = (blockIdx.z == 0) ? qmask : kmask;
            dst[bm + (t >> 2)] = (s != 0.0f) ? 1.0f : 0.0f;
        }
    }

    const float4 bias4 = *(const float4*)&bias[bn + tn];
    #pragma unroll
    for (int i = 0; i < 4; ++i) {
        const int row = bm + tm + i;
        float4 o;
        o.x = acc[i][0] + bias4.x; o.y = acc[i][1] + bias4.y;
        o.z = acc[i][2] + bias4.z; o.w = acc[i][3] + bias4.w;
        if (add) {
            const float4 a4 = *(const float4*)&add[row * 256 + bn + tn];
            o.x += a4.x; o.y += a4.y; o.z += a4.z; o.w += a4.w;
        }
        *(float4*)&out[row * 256 + bn + tn] = o;
    }
}

// ---------------------------------------------------------------------------
// Fused attention (R10 structure, unroll-4 deep pipeline).
// XCD-pinned: b = bid & 7; per-XCD q remap keeps per-CU work constant.
// ---------------------------------------------------------------------------
#define LP (L + 4)

__global__ __launch_bounds__(256) void attn_kernel(
    const float* __restrict__ Qm, const float* __restrict__ KPk,
    const float* __restrict__ VPv, const float* __restrict__ Tk,
    const float* __restrict__ Tv, const float* __restrict__ kmask,
    const float* __restrict__ qmask, const float* __restrict__ queries,
    float* __restrict__ out)
{
    const int bid = blockIdx.x;
    const int b   = bid & 7;                       // XCD-pinned batch
    const int j   = bid >> 3;                      // 0..255 within XCD
    const int g   = ((j & 192) >> 1) | (j & 31);
    const int q   = (j & 32) ? (255 - g) : g;
    const int bq  = (b << 8) + q;
    const int t    = threadIdx.x;
    const int w    = t >> 6;
    const int lane = t & 63;

    __shared__ float qrow[D];
    __shared__ float kmrow[L];
    __shared__ float sc[H][LP];
    __shared__ int   allneg[H];
    __shared__ float4 red[256];

    qrow[t]  = Qm[bq * D + t];
    kmrow[t] = kmask[(b << 8) + t];
    #pragma unroll
    for (int i = t; i < H * LP; i += 256) (&sc[0][0])[i] = NEGV;
    __syncthreads();

    // ---- Phase B: scores, block jointly streams consecutive KPk+Tk rows.
    const int hB = lane >> 3;
    const int jB = lane & 7;
    const size_t tbase = (size_t)bq << 16;
    const float4 qv = *(const float4*)&qrow[lane << 2];

    #pragma unroll 4
    for (int k = w; k <= q; k += 4) {
        const float4 kv  = *(const float4*)&KPk[((b << 8) + k) * 256 + (lane << 2)];
        const float4 tkv = *(const float4*)&Tk[tbase + ((size_t)k << 8) + (lane << 2)];
        float p = qv.x * (kv.x + tkv.x);
        p = fmaf(qv.y, kv.y + tkv.y, p);
        p = fmaf(qv.z, kv.z + tkv.z, p);
        p = fmaf(qv.w, kv.w + tkv.w, p);
        p += __shfl_xor(p, 1);
        p += __shfl_xor(p, 2);
        p += __shfl_xor(p, 4);
        if (jB == 0)
            sc[hB][k] = (kmrow[k] != 0.0f) ? p * INV_SQRT_DH : NEGV;
    }
    __syncthreads();

    // ---- Softmax: wave w handles heads 2w, 2w+1 (jax semantics).
    #pragma unroll
    for (int hh = 0; hh < 2; ++hh) {
        const int h = (w << 1) + hh;
        float v0 = sc[h][lane];
        float v1 = sc[h][lane + 64];
        float v2 = sc[h][lane + 128];
        float v3 = sc[h][lane + 192];
        float m = fmaxf(fmaxf(v0, v1), fmaxf(v2, v3));
        #pragma unroll
        for (int o = 1; o < 64; o <<= 1) m = fmaxf(m, __shfl_xor(m, o));
        const float e0 = __expf(v0 - m), e1 = __expf(v1 - m);
        const float e2 = __expf(v2 - m), e3 = __expf(v3 - m);
        float s = e0 + e1 + e2 + e3;
        #pragma unroll
        for (int o = 1; o < 64; o <<= 1) s += __shfl_xor(s, o);
        const float r = 1.0f / s;
        sc[h][lane]       = e0 * r;
        sc[h][lane + 64]  = e1 * r;
        sc[h][lane + 128] = e2 * r;
        sc[h][lane + 192] = e3 * r;
        if (lane == 0) allneg[h] = (m == NEGV) ? 1 : 0;
    }
    __syncthreads();

    // ---- Phase C: out = attn @ (VPv + Tv), 4-wave k-split.
    const int dg = lane;
    const int h  = dg >> 3;
    const int kmax = allneg[h] ? L : (q + 1);

    float4 acc = make_float4(0.f, 0.f, 0.f, 0.f);
    #pragma unroll 4
    for (int k = w; k < kmax; k += 4) {
        const float a = sc[h][k];
        const float4 v   = *(const float4*)&VPv[((b << 8) + k) * 256 + (dg << 2)];
        const float4 tvv = *(const float4*)&Tv[tbase + ((size_t)k << 8) + (dg << 2)];
        acc.x = fmaf(a, v.x + tvv.x, acc.x);
        acc.y = fmaf(a, v.y + tvv.y, acc.y);
        acc.z = fmaf(a, v.z + tvv.z, acc.z);
        acc.w = fmaf(a, v.w + tvv.w, acc.w);
    }
    red[t] = acc;
    __syncthreads();

    if (t < 64) {
        const float4 r0 = red[t], r1 = red[t + 64], r2 = red[t + 128], r3 = red[t + 192];
        const float qmv = qmask[bq];
        const float4 qv2 = *(const float4*)&queries[bq * 256 + (t << 2)];
        float4 o;
        o.x = (r0.x + r1.x + r2.x + r3.x) * qmv + qv2.x;
        o.y = (r0.y + r1.y + r2.y + r3.y) * qmv + qv2.y;
        o.z = (r0.z + r1.z + r2.z + r3.z) * qmv + qv2.z;
        o.w = (r0.w + r1.w + r2.w + r3.w) * qmv + qv2.w;
        *(float4*)&out[bq * 256 + (t << 2)] = o;
    }
}

// ---------------------------------------------------------------------------
extern "C" void kernel_launch(void* const* d_in, const int* in_sizes, int n_in,
                              void* d_out, int out_size, void* d_ws, size_t ws_size,
                              hipStream_t stream)
{
    const float* queries = (const float*)d_in[0];
    const float* keys    = (const float*)d_in[1];
    const float* Tk      = (const float*)d_in[2];
    const float* Tv      = (const float*)d_in[3];
    const float* pk      = (const float*)d_in[4];
    const float* pv      = (const float*)d_in[5];
    const float* Wq      = (const float*)d_in[6];
    const float* bq      = (const float*)d_in[7];
    const float* Wk      = (const float*)d_in[8];
    const float* bk      = (const float*)d_in[9];
    const float* Wv      = (const float*)d_in[10];
    const float* bv      = (const float*)d_in[11];
    float* out = (float*)d_out;

    float* ws  = (float*)d_ws;
    float* Q   = ws;                    // 2048*256
    float* KPk = ws + 524288;           // 2048*256
    float* VPv = ws + 1048576;          // 2048*256
    float* km  = ws + 1572864;           // 2048
    float* qm  = ws + 1574912;           // 2048

    dim3 pgrid(2048 / 64, 256 / 64, 3);
    proj3_kernel<<<pgrid, 256, 0, stream>>>(queries, keys, Wq, bq, Wk, bk,
                                            Wv, bv, pk, pv, Q, KPk, VPv,
                                            km, qm);
    attn_kernel<<<2048, 256, 0, stream>>>(Q, KPk, VPv, Tk, Tv, km, qm,
                                          queries, out);
}